// Round 1
// baseline (805.343 us; speedup 1.0000x reference)
//
#include <hip/hip_runtime.h>
#include <cstdint>

#define C_DIM 256
#define EPS 1e-5f

typedef __attribute__((ext_vector_type(8))) short short8;
typedef __attribute__((ext_vector_type(4))) float f32x4;

__device__ __forceinline__ ushort f2bf(float f) {
  uint32_t u = __float_as_uint(f);
  u = (u + 0x7fffu + ((u >> 16) & 1u)) >> 16;
  return (ushort)u;
}
__device__ __forceinline__ float bflo(uint32_t p) { return __uint_as_float(p << 16); }
__device__ __forceinline__ float bfhi(uint32_t p) { return __uint_as_float(p & 0xffff0000u); }

// ---------------- setup kernels (unchanged, proven) ----------------
__global__ void k_count(const int* __restrict__ col, int E, int* cnt) {
  int e = blockIdx.x * blockDim.x + threadIdx.x;
  if (e < E) atomicAdd(&cnt[col[e]], 1);
}

__global__ void k_isd(int* cnt, float* isd, int n) {
  int i = blockIdx.x * blockDim.x + threadIdx.x;
  if (i < n) { isd[i] = rsqrtf((float)(cnt[i] + 1)); cnt[i] = 0; }
}

__global__ void k_scan1(const int* __restrict__ cnt, int* excl, int* bsum, int n) {
  __shared__ int s[1024];
  int i = blockIdx.x * 1024 + threadIdx.x;
  int v = (i < n) ? cnt[i] : 0;
  s[threadIdx.x] = v;
  __syncthreads();
  for (int off = 1; off < 1024; off <<= 1) {
    int t = (threadIdx.x >= off) ? s[threadIdx.x - off] : 0;
    __syncthreads();
    s[threadIdx.x] += t;
    __syncthreads();
  }
  if (i < n) excl[i] = s[threadIdx.x] - v;
  if (threadIdx.x == 1023) bsum[blockIdx.x] = s[1023];
}

__global__ void k_scan2(int* bsum, int nb) {
  __shared__ int s[1024];
  int v = (threadIdx.x < nb) ? bsum[threadIdx.x] : 0;
  s[threadIdx.x] = v;
  __syncthreads();
  for (int off = 1; off < 1024; off <<= 1) {
    int t = (threadIdx.x >= off) ? s[threadIdx.x - off] : 0;
    __syncthreads();
    s[threadIdx.x] += t;
    __syncthreads();
  }
  if (threadIdx.x < nb) bsum[threadIdx.x] = s[threadIdx.x] - v;
}

__global__ void k_scan3(int* excl, const int* __restrict__ bsum, int n, int E) {
  int i = blockIdx.x * 1024 + threadIdx.x;
  if (i < n) excl[i] += bsum[blockIdx.x];
  if (i == 0) excl[n] = E;
}

__global__ void k_fill(const int* __restrict__ row, const int* __restrict__ col, int E,
                       const int* __restrict__ row_ptr, int* cursor,
                       const float* __restrict__ isd, int2* __restrict__ edat) {
  int e = blockIdx.x * blockDim.x + threadIdx.x;
  if (e < E) {
    int d = col[e], s = row[e];
    int p = row_ptr[d] + atomicAdd(&cursor[d], 1);
    edat[p] = make_int2(s, __float_as_int(isd[s] * isd[d]));
  }
}

__global__ void k_cvt_x(const float* __restrict__ x, ushort* __restrict__ xb, int n4) {
  int i = blockIdx.x * blockDim.x + threadIdx.x;
  if (i < n4) {
    float4 v = ((const float4*)x)[i];
    ushort4 o;
    o.x = f2bf(v.x); o.y = f2bf(v.y); o.z = f2bf(v.z); o.w = f2bf(v.w);
    ((ushort4*)xb)[i] = o;
  }
}

__global__ void k_cvt_w(const float* __restrict__ W1, const float* __restrict__ W2,
                        ushort* __restrict__ Wt1, ushort* __restrict__ Wt2) {
  int i = blockIdx.x * blockDim.x + threadIdx.x;
  int n = i >> 8, k = i & 255;
  Wt1[i] = f2bf(W1[k * 256 + n]);
  Wt2[i] = f2bf(W2[k * 256 + n]);
}

// ---------------- pure gather-aggregate: ax = D^-1/2 (A+I) D^-1/2 x ----------------
// (LN/bias/ReLU moved into the GEMM epilogue via linearity agg(xW) = agg(x)W)
__global__ __launch_bounds__(256) void k_agg(const ushort* __restrict__ xb,
    const int2* __restrict__ edat, const int* __restrict__ row_ptr,
    const float* __restrict__ isd, ushort* __restrict__ axb, int n) {
  int i = blockIdx.x * 4 + (threadIdx.x >> 6);
  int lane = threadIdx.x & 63;
  if (i >= n) return;
  const uint2* x2 = (const uint2*)xb;  // 8B = 4 bf16 channels per lane

  float si = isd[i];
  float sn = si * si;
  uint2 p = x2[(size_t)i * 64 + lane];
  float a0 = bflo(p.x) * sn, a1 = bfhi(p.x) * sn;
  float a2 = bflo(p.y) * sn, a3 = bfhi(p.y) * sn;

  int e0 = row_ptr[i], e1 = row_ptr[i + 1];
  int e = e0;
  // 4-deep unroll: 4 independent 512B row-gathers in flight per wave
  for (; e + 3 < e1; e += 4) {
    int2 ed0 = edat[e], ed1 = edat[e + 1], ed2 = edat[e + 2], ed3 = edat[e + 3];
    uint2 v0 = x2[(size_t)ed0.x * 64 + lane];
    uint2 v1 = x2[(size_t)ed1.x * 64 + lane];
    uint2 v2 = x2[(size_t)ed2.x * 64 + lane];
    uint2 v3 = x2[(size_t)ed3.x * 64 + lane];
    float w0 = __int_as_float(ed0.y), w1 = __int_as_float(ed1.y);
    float w2 = __int_as_float(ed2.y), w3 = __int_as_float(ed3.y);
    a0 += bflo(v0.x) * w0 + bflo(v1.x) * w1 + bflo(v2.x) * w2 + bflo(v3.x) * w3;
    a1 += bfhi(v0.x) * w0 + bfhi(v1.x) * w1 + bfhi(v2.x) * w2 + bfhi(v3.x) * w3;
    a2 += bflo(v0.y) * w0 + bflo(v1.y) * w1 + bflo(v2.y) * w2 + bflo(v3.y) * w3;
    a3 += bfhi(v0.y) * w0 + bfhi(v1.y) * w1 + bfhi(v2.y) * w2 + bfhi(v3.y) * w3;
  }
  for (; e < e1; e++) {
    int2 ed = edat[e];
    float w0 = __int_as_float(ed.y);
    uint2 v0 = x2[(size_t)ed.x * 64 + lane];
    a0 += bflo(v0.x) * w0; a1 += bfhi(v0.x) * w0;
    a2 += bflo(v0.y) * w0; a3 += bfhi(v0.y) * w0;
  }

  uint2 q;
  q.x = (uint32_t)f2bf(a0) | ((uint32_t)f2bf(a1) << 16);
  q.y = (uint32_t)f2bf(a2) | ((uint32_t)f2bf(a3) << 16);
  ((uint2*)axb)[(size_t)i * 64 + lane] = q;
}

// ---------------- full-row GEMM with fused bias + LN + ReLU epilogue ----------------
// C[128 rows][256 cols] per block, 8 waves (2 row-groups x 4 col-groups of 64x64)
__global__ __launch_bounds__(512) void k_gemm_ln(const ushort* __restrict__ A,
    const ushort* __restrict__ Wt, const float* __restrict__ bias,
    const float* __restrict__ gamma, const float* __restrict__ beta,
    float* __restrict__ out, ushort* __restrict__ outb, int M) {
  __shared__ ushort As[128 * 64];   // 16 KB
  __shared__ ushort Bs[256 * 64];   // 32 KB
  const int tid = threadIdx.x;
  const int wave = tid >> 6, lane = tid & 63;
  const int bm = blockIdx.x * 128;
  const int wm = (wave >> 2) * 64, wn = (wave & 3) * 64;

  f32x4 acc[4][4] = {};
  const int r_off = lane >> 3;  // 0..7 rows per 1KB staging inst
  const int cc = lane & 7;      // 16B chunk slot within 128B row

  for (int k0 = 0; k0 < C_DIM; k0 += 64) {
    // 48 staging insts (16 As row-blocks + 32 Bs row-blocks) over 8 waves
#pragma unroll
    for (int j = 0; j < 6; j++) {
      int q = wave * 6 + j;
      if (q < 16) {
        int rl = q * 8 + r_off;
        int c = cc ^ (rl & 7);               // swizzled source chunk
        int gm = bm + rl; if (gm >= M) gm = M - 1;
        const ushort* ga = &A[(size_t)gm * C_DIM + k0 + c * 8];
        ushort* la = &As[q * 8 * 64];
        __builtin_amdgcn_global_load_lds((const __attribute__((address_space(1))) void*)ga,
                                         (__attribute__((address_space(3))) void*)la, 16, 0, 0);
      } else {
        int rl = (q - 16) * 8 + r_off;       // B row = output col, 0..255 always valid
        int c = cc ^ (rl & 7);
        const ushort* gb = &Wt[(size_t)rl * C_DIM + k0 + c * 8];
        ushort* lb = &Bs[(q - 16) * 8 * 64];
        __builtin_amdgcn_global_load_lds((const __attribute__((address_space(1))) void*)gb,
                                         (__attribute__((address_space(3))) void*)lb, 16, 0, 0);
      }
    }
    __syncthreads();
#pragma unroll
    for (int s = 0; s < 2; s++) {
      short8 af[4], bfr[4];
      int ca = s * 4 + (lane >> 4);
#pragma unroll
      for (int t = 0; t < 4; t++) {
        int ra = wm + t * 16 + (lane & 15);
        af[t] = *(const short8*)&As[ra * 64 + ((ca ^ (ra & 7)) << 3)];
        int rb = wn + t * 16 + (lane & 15);
        bfr[t] = *(const short8*)&Bs[rb * 64 + ((ca ^ (rb & 7)) << 3)];
      }
#pragma unroll
      for (int mt = 0; mt < 4; mt++)
#pragma unroll
        for (int nt = 0; nt < 4; nt++)
          acc[mt][nt] = __builtin_amdgcn_mfma_f32_16x16x32_bf16(af[mt], bfr[nt], acc[mt][nt], 0, 0, 0);
    }
    __syncthreads();
  }

  // ---- fused epilogue: + bias, LayerNorm over the 256-wide row, ReLU ----
  // C/D layout: col = lane&15, row = (lane>>4)*4 + reg  (m89-verified)
#pragma unroll
  for (int nt = 0; nt < 4; nt++) {
    float bcol = bias[wn + nt * 16 + (lane & 15)];
#pragma unroll
    for (int mt = 0; mt < 4; mt++)
#pragma unroll
      for (int r = 0; r < 4; r++)
        acc[mt][nt][r] += bcol;
  }

  // per-row partials over this wave's 64 cols, reduced across the 16 lanes of a quarter
  float psum[4][4], psq[4][4];
#pragma unroll
  for (int mt = 0; mt < 4; mt++)
#pragma unroll
    for (int r = 0; r < 4; r++) {
      float s = 0.0f, q2 = 0.0f;
#pragma unroll
      for (int nt = 0; nt < 4; nt++) {
        float v = acc[mt][nt][r];
        s += v; q2 += v * v;
      }
#pragma unroll
      for (int off = 1; off <= 8; off <<= 1) {
        s += __shfl_xor(s, off, 64);
        q2 += __shfl_xor(q2, off, 64);
      }
      psum[mt][r] = s; psq[mt][r] = q2;
    }

  // combine across the 4 col-waves via LDS (reuse As region; K-loop ended with a barrier)
  float* red = (float*)As;  // [128 rows][4 col-waves] sums, +512 floats: sumsq
  if ((lane & 15) == 0) {
    int qr = lane >> 4;
#pragma unroll
    for (int mt = 0; mt < 4; mt++)
#pragma unroll
      for (int r = 0; r < 4; r++) {
        int row = wm + mt * 16 + qr * 4 + r;
        red[row * 4 + (wave & 3)] = psum[mt][r];
        red[512 + row * 4 + (wave & 3)] = psq[mt][r];
      }
  }
  __syncthreads();

  float mu[4][4], rs[4][4];
#pragma unroll
  for (int mt = 0; mt < 4; mt++)
#pragma unroll
    for (int r = 0; r < 4; r++) {
      int row = wm + mt * 16 + (lane >> 4) * 4 + r;
      float s  = red[row * 4 + 0] + red[row * 4 + 1] + red[row * 4 + 2] + red[row * 4 + 3];
      float q2 = red[512 + row * 4 + 0] + red[512 + row * 4 + 1] +
                 red[512 + row * 4 + 2] + red[512 + row * 4 + 3];
      float m = s * (1.0f / C_DIM);
      mu[mt][r] = m;
      rs[mt][r] = rsqrtf(q2 * (1.0f / C_DIM) - m * m + EPS);
    }

#pragma unroll
  for (int nt = 0; nt < 4; nt++) {
    int col = wn + nt * 16 + (lane & 15);
    float g = gamma[col], bt = beta[col];
#pragma unroll
    for (int mt = 0; mt < 4; mt++) {
      int row0 = bm + wm + mt * 16 + ((lane >> 4) << 2);
#pragma unroll
      for (int r = 0; r < 4; r++) {
        int row = row0 + r;
        if (row < M) {
          float v = fmaxf((acc[mt][nt][r] - mu[mt][r]) * rs[mt][r] * g + bt, 0.0f);
          // z is final output, never re-read on-device: bypass cache pollution
          __builtin_nontemporal_store(v, &out[(size_t)row * C_DIM + col]);
          if (outb) outb[(size_t)row * C_DIM + col] = f2bf(v);
        }
      }
    }
  }
}

// ---------------- host ----------------
extern "C" void kernel_launch(void* const* d_in, const int* in_sizes, int n_in,
                              void* d_out, int out_size, void* d_ws, size_t ws_size,
                              hipStream_t stream) {
  const float* x = (const float*)d_in[0];
  const int* edges = (const int*)d_in[1];
  const float* W1 = (const float*)d_in[2];
  const float* b1 = (const float*)d_in[3];
  const float* W2 = (const float*)d_in[4];
  const float* b2 = (const float*)d_in[5];
  const float* gamma = (const float*)d_in[6];
  const float* beta = (const float*)d_in[7];

  int N = in_sizes[0] / C_DIM;
  int E = in_sizes[1] / 2;
  const int* row = edges;
  const int* col = edges + E;

  char* ws = (char*)d_ws;
  size_t off = 0;
  auto alloc = [&](size_t bytes) -> void* {
    void* p = ws + off;
    off = (off + bytes + 255) & ~(size_t)255;
    return p;
  };
  ushort* xb  = (ushort*)alloc((size_t)N * C_DIM * 2);  // x bf16; reused as z1 bf16
  ushort* axb = (ushort*)alloc((size_t)N * C_DIM * 2);  // aggregated bf16 (GEMM A operand)
  ushort* Wt1 = (ushort*)alloc(65536 * 2);
  ushort* Wt2 = (ushort*)alloc(65536 * 2);
  int* cnt = (int*)alloc((size_t)N * 4);                 // reused as fill cursor
  float* isd = (float*)alloc((size_t)N * 4);
  int* row_ptr = (int*)alloc((size_t)(N + 1) * 4);
  int nb = (N + 1023) / 1024;
  int* bsum = (int*)alloc((size_t)nb * 4);
  int2* edat = (int2*)alloc((size_t)E * 8);              // packed (src, nrm)

  float* z1 = (float*)d_out;
  float* z2 = (float*)d_out + (size_t)N * C_DIM;

  // conversions
  int n4 = N * C_DIM / 4;
  k_cvt_x<<<(n4 + 255) / 256, 256, 0, stream>>>(x, xb, n4);
  k_cvt_w<<<256, 256, 0, stream>>>(W1, W2, Wt1, Wt2);

  // CSR build (shared by both layers)
  hipMemsetAsync(cnt, 0, (size_t)N * 4, stream);
  k_count<<<(E + 255) / 256, 256, 0, stream>>>(col, E, cnt);
  k_scan1<<<nb, 1024, 0, stream>>>(cnt, row_ptr, bsum, N);
  k_scan2<<<1, 1024, 0, stream>>>(bsum, nb);
  k_scan3<<<nb, 1024, 0, stream>>>(row_ptr, bsum, N, E);
  k_isd<<<(N + 255) / 256, 256, 0, stream>>>(cnt, isd, N);  // zeroes cnt -> cursor
  k_fill<<<(E + 255) / 256, 256, 0, stream>>>(row, col, E, row_ptr, cnt, isd, edat);

  int agg_blocks = (N + 3) / 4;
  dim3 ggrid((N + 127) / 128);

  // layer 1: agg(x) then [agg @ W1 + b1 -> LN -> ReLU]  (agg(xW) == agg(x)W by linearity)
  k_agg<<<agg_blocks, 256, 0, stream>>>(xb, edat, row_ptr, isd, axb, N);
  k_gemm_ln<<<ggrid, 512, 0, stream>>>(axb, Wt1, b1, gamma, beta, z1, xb, N);
  // layer 2 (xb now holds z1 in bf16)
  k_agg<<<agg_blocks, 256, 0, stream>>>(xb, edat, row_ptr, isd, axb, N);
  k_gemm_ln<<<ggrid, 512, 0, stream>>>(axb, Wt2, b2, gamma, beta, z2, nullptr, N);
}